// Round 1
// baseline (433.449 us; speedup 1.0000x reference)
//
#include <hip/hip_runtime.h>
#include <cstdint>

#define MUL0 16
#define MUL1 8
#define NRBF 8
#define HID 64
#define WNUM 576
#define CUTOFF 5.0f
#define EPSF 1e-8f

#define INV_SQRT3 0.57735026918962576f
#define A_PATH    0.20412414523193154f   /* 1/sqrt(24) */
#define Q16       0.25f                  /* 1/sqrt(16) */
#define Q8        0.35355339059327373f   /* 1/sqrt(8)  */
#define PI_OVER_CUT 0.62831853071795865f /* pi/5 */

typedef _Float16 f16;
typedef _Float16 f16x8 __attribute__((ext_vector_type(8)));
typedef float f32x4 __attribute__((ext_vector_type(4)));

__device__ __forceinline__ float sigm(float x) { return 1.0f / (1.0f + __expf(-x)); }

// ---------------- prep: w_r2 (64 x 576 f32) -> W2T (576 x 64 f16) ----------------
extern "C" __global__ __launch_bounds__(256) void k_prep_w2t(
    const float* __restrict__ w_r2, f16* __restrict__ W2T) {
  int t = blockIdx.x * 256 + threadIdx.x;
  if (t >= HID * WNUM) return;
  int n = t >> 6, k = t & 63;
  W2T[n * 64 + k] = (f16)w_r2[k * WNUM + n];
}

// ---------------- node irrep norm ----------------
extern "C" __global__ __launch_bounds__(256) void k_xnorm(
    const float* __restrict__ x, float* __restrict__ xnorm, int N) {
  int n = blockIdx.x * 256 + threadIdx.x;
  if (n >= N) return;
  const float* xr = x + (long long)n * 40;
  float* o = xnorm + (long long)n * 40;
  float v[40];
  float ss = 0.f, vs = 0.f;
#pragma unroll
  for (int i = 0; i < 16; i++) { v[i] = xr[i]; ss += v[i] * v[i]; }
#pragma unroll
  for (int i = 16; i < 40; i++) { v[i] = xr[i]; vs += v[i] * v[i]; }
  float sr = rsqrtf(ss * (1.0f / 16.0f) + EPSF);
  float vr = rsqrtf(vs * (1.0f / 8.0f) + EPSF);
#pragma unroll
  for (int i = 0; i < 16; i++) o[i] = v[i] * sr;
#pragma unroll
  for (int i = 16; i < 40; i++) o[i] = v[i] * vr;
}

// ---------------- fused edge kernel ----------------
// block = 256 threads, handles 64 edges. Each wave owns 16 edges.
extern "C" __global__ __launch_bounds__(256) void k_edge(
    const float* __restrict__ xnorm, const int* __restrict__ esrc,
    const int* __restrict__ edst, const float* __restrict__ sh,
    const float* __restrict__ rbf, const float* __restrict__ elen,
    const float* __restrict__ w_r1, const float* __restrict__ b_r1,
    const float* __restrict__ w_g1, const float* __restrict__ b_g1,
    const float* __restrict__ w_g2, const float* __restrict__ b_g2,
    const float* __restrict__ b_r2, const f16* __restrict__ W2T,
    float* __restrict__ agg0, float* __restrict__ agg1,
    float* __restrict__ normb, int E) {
  __shared__ float s_rbf[64][NRBF];
  __shared__ float s_sh[64][4];
  __shared__ int s_src[64];
  __shared__ int s_dst[64];
  __shared__ float s_ew[64];
  __shared__ float s_a0[64][16];
  __shared__ float s_a1[64][8];
  __shared__ float s_sn[64][16];
  __shared__ float s_vsh[64][24];
  __shared__ __align__(16) f16 s_H[64][64];
  __shared__ float s_br2[WNUM];

  const int t = threadIdx.x;
  const long long eb = (long long)blockIdx.x * 64;

  // ---- phase 0: cooperative staging ----
  {
    float* pr = &s_rbf[0][0];
    for (int i = t; i < 64 * NRBF; i += 256) {
      long long g = eb * NRBF + i;
      pr[i] = (g < (long long)E * NRBF) ? rbf[g] : 0.f;
    }
    float* ps = &s_sh[0][0];
    for (int i = t; i < 256; i += 256) {
      long long g = eb * 4 + i;
      ps[i] = (g < (long long)E * 4) ? sh[g] : 0.f;
    }
    for (int i = t; i < WNUM; i += 256) s_br2[i] = b_r2[i];
    if (t < 64) {
      long long g = eb + t;
      s_src[t] = (g < E) ? esrc[g] : 0;
      s_dst[t] = (g < E) ? edst[g] : 0;
    }
  }
  __syncthreads();

  // ---- phase A1: hidden layer H (f16), all 256 threads ----
  {
    int h = t & 63, grp = t >> 6;
    float wr[NRBF];
#pragma unroll
    for (int r = 0; r < NRBF; r++) wr[r] = w_r1[r * HID + h];
    float bh = b_r1[h];
    for (int u = 0; u < 16; u++) {
      int e = grp * 16 + u;
      float acc = bh;
#pragma unroll
      for (int r = 0; r < NRBF; r++) acc += s_rbf[e][r] * wr[r];
      s_H[e][h] = (f16)(acc * sigm(acc));
    }
  }

  // ---- phase A2: gathers + gate MLP ----
  if (t < 64) {
    int e = t;
    const float* xr = xnorm + (long long)s_src[e] * 40;
    float sh0 = s_sh[e][0], s1x = s_sh[e][1], s1y = s_sh[e][2], s1z = s_sh[e][3];
#pragma unroll
    for (int i = 0; i < 16; i++) {
      float s = xr[i];
      s_sn[e][i] = s;
      s_a0[e][i] = s * sh0;
    }
#pragma unroll
    for (int i = 0; i < 8; i++) {
      float vx = xr[16 + 3 * i], vy = xr[17 + 3 * i], vz = xr[18 + 3 * i];
      s_a1[e][i] = INV_SQRT3 * (vx * s1x + vy * s1y + vz * s1z);
      s_vsh[e][3 * i] = vx * sh0;
      s_vsh[e][3 * i + 1] = vy * sh0;
      s_vsh[e][3 * i + 2] = vz * sh0;
    }
  } else if (t < 128) {
    int e = t - 64;
    long long g = eb + e;
    float acc = 0.f;
    for (int k = 0; k < HID; k++) {
      float tt = b_g1[k];
#pragma unroll
      for (int r = 0; r < NRBF; r++) tt += s_rbf[e][r] * w_g1[r * HID + k];
      acc += tt * sigm(tt) * w_g2[k];
    }
    float ew = 0.f;
    if (g < E) {
      float len = elen[g];
      float cw = (len < CUTOFF) ? 0.5f * (__cosf(PI_OVER_CUT * len) + 1.0f) : 0.f;
      ew = cw * sigm(acc + b_g2[0]);
    }
    s_ew[e] = ew;
  }
  __syncthreads();

  // ---- phase B: MFMA over 36 j-tiles, fused contraction ----
  const int lane = t & 63;
  const int wv = t >> 6;
  const int quad = lane >> 4;
  const int c = lane & 15;
  const int e0 = wv * 16;

  const f16x8 af0 = *(const f16x8*)&s_H[e0 + c][quad * 8];
  const f16x8 af1 = *(const f16x8*)&s_H[e0 + c][32 + quad * 8];

  float m0a[4] = {0.f, 0.f, 0.f, 0.f};
  float t3a[4] = {0.f, 0.f, 0.f, 0.f};
  float m1x[4] = {0.f, 0.f, 0.f, 0.f};
  float m1y[4] = {0.f, 0.f, 0.f, 0.f};
  float m1z[4] = {0.f, 0.f, 0.f, 0.f};

  const f16* wb = W2T + (long long)c * 64 + quad * 8;

  for (int jt = 0; jt < 36; jt++) {
    const f16x8 b0 = *(const f16x8*)(wb + jt * 1024);
    const f16x8 b1 = *(const f16x8*)(wb + jt * 1024 + 32);
    f32x4 C = {0.f, 0.f, 0.f, 0.f};
    C = __builtin_amdgcn_mfma_f32_16x16x32_f16(af0, b0, C, 0, 0, 0);
    C = __builtin_amdgcn_mfma_f32_16x16x32_f16(af1, b1, C, 0, 0, 0);
    float bias = s_br2[jt * 16 + c];
    if (jt < 16) {
#pragma unroll
      for (int r = 0; r < 4; r++) {
        int e = e0 + quad * 4 + r;
        m0a[r] += s_a0[e][jt] * (C[r] + bias);
      }
    } else if (jt < 24) {
      int i = jt - 16;
#pragma unroll
      for (int r = 0; r < 4; r++) {
        int e = e0 + quad * 4 + r;
        m0a[r] += s_a1[e][i] * (C[r] + bias);
      }
    } else if (jt < 32) {
      int i = (jt - 24) * 2 + (c >> 3);
#pragma unroll
      for (int r = 0; r < 4; r++) {
        int e = e0 + quad * 4 + r;
        t3a[r] += s_sn[e][i] * (C[r] + bias);
      }
    } else {
      int i = (jt - 32) * 2 + (c >> 3);
#pragma unroll
      for (int r = 0; r < 4; r++) {
        int e = e0 + quad * 4 + r;
        float wvv = C[r] + bias;
        m1x[r] += s_vsh[e][3 * i] * wvv;
        m1y[r] += s_vsh[e][3 * i + 1] * wvv;
        m1z[r] += s_vsh[e][3 * i + 2] * wvv;
      }
    }
  }

  // fold the two column-halves (c and c^8 share the same output j = c&7)
#pragma unroll
  for (int r = 0; r < 4; r++) {
    t3a[r] += __shfl_xor(t3a[r], 8, 64);
    m1x[r] += __shfl_xor(m1x[r], 8, 64);
    m1y[r] += __shfl_xor(m1y[r], 8, 64);
    m1z[r] += __shfl_xor(m1z[r], 8, 64);
  }

  // ---- epilogue: scale + atomic scatter ----
#pragma unroll
  for (int r = 0; r < 4; r++) {
    int e = e0 + quad * 4 + r;
    float ew = s_ew[e];
    float sc = A_PATH * ew;
    int dst = s_dst[e];
    atomicAdd(&agg0[(long long)dst * 16 + c], m0a[r] * sc);
    if (c < 8) {
      float t3v = t3a[r] * sc;
      float ox = t3v * s_sh[e][1] + m1x[r] * sc;
      float oy = t3v * s_sh[e][2] + m1y[r] * sc;
      float oz = t3v * s_sh[e][3] + m1z[r] * sc;
      long long b = (long long)dst * 24 + c * 3;
      atomicAdd(&agg1[b], ox);
      atomicAdd(&agg1[b + 1], oy);
      atomicAdd(&agg1[b + 2], oz);
    } else if (c == 8) {
      atomicAdd(&normb[dst], ew);
    }
  }
}

// ---------------- final node kernel ----------------
extern "C" __global__ __launch_bounds__(256) void k_node(
    const float* __restrict__ x, const float* __restrict__ xnorm,
    const float* __restrict__ agg0, const float* __restrict__ agg1,
    const float* __restrict__ normb, const float* __restrict__ Wm_s,
    const float* __restrict__ Wm_v, const float* __restrict__ Wu_s,
    const float* __restrict__ Wu_v, const float* __restrict__ Ws_s,
    const float* __restrict__ Ws_v, const float* __restrict__ res_scale_p,
    float* __restrict__ out, int N) {
  __shared__ float sWms[16 * 24];
  __shared__ float sWmv[64];
  __shared__ float sWus[256];
  __shared__ float sWuv[64];
  __shared__ float sWss[256];
  __shared__ float sWsv[64];
  int t = threadIdx.x;
  for (int i = t; i < 384; i += 256) sWms[i] = Wm_s[i];
  for (int i = t; i < 64; i += 256) sWmv[i] = Wm_v[i];
  for (int i = t; i < 256; i += 256) sWus[i] = Wu_s[i];
  for (int i = t; i < 64; i += 256) sWuv[i] = Wu_v[i];
  for (int i = t; i < 256; i += 256) sWss[i] = Ws_s[i];
  for (int i = t; i < 64; i += 256) sWsv[i] = Ws_v[i];
  __syncthreads();
  int n = blockIdx.x * 256 + t;
  if (n >= N) return;

  float inv = 1.0f / fmaxf(normb[n], EPSF);
  float a0[16], a1[24];
#pragma unroll
  for (int i = 0; i < 16; i++) a0[i] = agg0[(long long)n * 16 + i] * inv;
#pragma unroll
  for (int i = 0; i < 24; i++) a1[i] = agg1[(long long)n * 24 + i] * inv;

  float scal[16], gate[8];
#pragma unroll
  for (int jj = 0; jj < 24; jj++) {
    float acc = 0.f;
#pragma unroll
    for (int i = 0; i < 16; i++) acc += a0[i] * sWms[i * 24 + jj];
    acc *= Q16;
    if (jj < 16) scal[jj] = acc * sigm(acc);
    else gate[jj - 16] = sigm(acc);
  }
  float vg[24];
#pragma unroll
  for (int j = 0; j < 8; j++) {
    float g = gate[j];
#pragma unroll
    for (int cc = 0; cc < 3; cc++) {
      float acc = 0.f;
#pragma unroll
      for (int i = 0; i < 8; i++) acc += a1[i * 3 + cc] * sWmv[i * 8 + j];
      vg[j * 3 + cc] = acc * Q8 * g;
    }
  }
  const float* xn = xnorm + (long long)n * 40;
  const float* xo = x + (long long)n * 40;
  float rs = res_scale_p[0];
  float xs[16];
#pragma unroll
  for (int i = 0; i < 16; i++) xs[i] = xn[i];
#pragma unroll
  for (int j = 0; j < 16; j++) {
    float acc = 0.f, acc2 = 0.f;
#pragma unroll
    for (int i = 0; i < 16; i++) {
      acc += scal[i] * sWus[i * 16 + j];
      acc2 += xs[i] * sWss[i * 16 + j];
    }
    out[(long long)n * 40 + j] = xo[j] + rs * ((acc + acc2) * Q16);
  }
  float xv[24];
#pragma unroll
  for (int i = 0; i < 24; i++) xv[i] = xn[16 + i];
#pragma unroll
  for (int j = 0; j < 8; j++) {
#pragma unroll
    for (int cc = 0; cc < 3; cc++) {
      float acc = 0.f;
#pragma unroll
      for (int i = 0; i < 8; i++)
        acc += vg[i * 3 + cc] * sWuv[i * 8 + j] + xv[i * 3 + cc] * sWsv[i * 8 + j];
      out[(long long)n * 40 + 16 + j * 3 + cc] = xo[16 + j * 3 + cc] + rs * (acc * Q8);
    }
  }
}

// ---------------- launch ----------------
extern "C" void kernel_launch(void* const* d_in, const int* in_sizes, int n_in,
                              void* d_out, int out_size, void* d_ws, size_t ws_size,
                              hipStream_t stream) {
  const float* x = (const float*)d_in[0];
  const int* esrc = (const int*)d_in[1];
  const int* edst = (const int*)d_in[2];
  const float* sh = (const float*)d_in[3];
  const float* rbf = (const float*)d_in[4];
  const float* elen = (const float*)d_in[5];
  const float* w_r1 = (const float*)d_in[6];
  const float* b_r1 = (const float*)d_in[7];
  const float* w_r2 = (const float*)d_in[8];
  const float* b_r2 = (const float*)d_in[9];
  const float* w_g1 = (const float*)d_in[10];
  const float* b_g1 = (const float*)d_in[11];
  const float* w_g2 = (const float*)d_in[12];
  const float* b_g2 = (const float*)d_in[13];
  const float* Wm_s = (const float*)d_in[14];
  const float* Wm_v = (const float*)d_in[15];
  const float* Wu_s = (const float*)d_in[16];
  const float* Wu_v = (const float*)d_in[17];
  const float* Ws_s = (const float*)d_in[18];
  const float* Ws_v = (const float*)d_in[19];
  const float* res_scale = (const float*)d_in[20];

  const int N = in_sizes[0] / 40;
  const int E = in_sizes[1];

  char* ws = (char*)d_ws;
  size_t off = 0;
  float* xnorm = (float*)(ws + off); off += (size_t)N * 40 * sizeof(float);
  off = (off + 255) & ~(size_t)255;
  float* agg0 = (float*)(ws + off); off += (size_t)N * 16 * sizeof(float);
  float* agg1 = (float*)(ws + off); off += (size_t)N * 24 * sizeof(float);
  float* normb = (float*)(ws + off); off += (size_t)N * sizeof(float);
  off = (off + 255) & ~(size_t)255;
  f16* W2T = (f16*)(ws + off); off += (size_t)WNUM * 64 * sizeof(f16);

  // zero accumulators (agg0, agg1, normb are contiguous)
  hipMemsetAsync(agg0, 0, (size_t)N * 41 * sizeof(float), stream);

  k_prep_w2t<<<(HID * WNUM + 255) / 256, 256, 0, stream>>>(w_r2, W2T);
  k_xnorm<<<(N + 255) / 256, 256, 0, stream>>>(x, xnorm, N);

  int nblk = (E + 63) / 64;
  k_edge<<<nblk, 256, 0, stream>>>(xnorm, esrc, edst, sh, rbf, elen, w_r1, b_r1,
                                   w_g1, b_g1, w_g2, b_g2, b_r2, W2T, agg0, agg1,
                                   normb, E);

  k_node<<<(N + 255) / 256, 256, 0, stream>>>(x, xnorm, agg0, agg1, normb, Wm_s,
                                              Wm_v, Wu_s, Wu_v, Ws_s, Ws_v,
                                              res_scale, (float*)d_out, N);
}